// Round 7
// baseline (1524.384 us; speedup 1.0000x reference)
//
#include <hip/hip_runtime.h>
#include <hip/hip_cooperative_groups.h>
#include <cstdint>
#include <cstddef>
#include <cmath>

namespace cg = cooperative_groups;

typedef __bf16 bf16_t;
typedef __bf16 bf16x8 __attribute__((ext_vector_type(8)));
typedef float floatx4 __attribute__((ext_vector_type(4)));

#define AS1 __attribute__((address_space(1)))
#define AS3 __attribute__((address_space(3)))

__device__ __forceinline__ void gload_lds16(const bf16_t* g, bf16_t* l) {
    __builtin_amdgcn_global_load_lds((AS1 void*)(uintptr_t)(g), (AS3 void*)(l), 16, 0, 0);
}

__device__ __forceinline__ float sigf(float x) { return 1.0f / (1.0f + __expf(-x)); }
__device__ __forceinline__ float tanhfast(float x) { return 1.0f - 2.0f / (__expf(2.0f * x) + 1.0f); }

// ================= shared GEMM+LSTM tile (device fn, used by mega) =================
// gates = A(M,1152) @ W(N,1152)^T + bias, LSTM cell fused in epilogue.
// A split at xlim (mult of 64): cols [0,xlim) from Ax, [xlim,1152) from Ah
// (h double-buffered across layers). Gate-interleaved W: lane's acc[i][0..3]
// = (i,f,g,o) of element e = ((n0+wn)>>2)+(lane&15). LDS XOR swizzle: phys
// 16B chunk = logical ^ (row&7); staging keeps linear base+lane*16 LDS
// addresses (global_load_lds requirement) by permuting global addresses.
// c transposed [e][4096] so epilogue c access is float4.
template<int BM>
__device__ __forceinline__ void gemm_lstm_phase(
    const bf16_t* __restrict__ Ax, int ldX, int xlim,
    const bf16_t* __restrict__ Ah, int ldHin,
    const bf16_t* __restrict__ W, const float* __restrict__ bias,
    float* __restrict__ c,
    bf16_t* __restrict__ hb, float* __restrict__ hf, int ldHo, int relu,
    int bx, int by, bf16_t* As, bf16_t* Bs)
{
    constexpr int AI = BM / 32;
    constexpr int K  = 1152;
    const int tid  = threadIdx.x;
    const int lane = tid & 63;
    const int w    = tid >> 6;
    const int wm   = (w & 1) * (BM / 2);
    const int wn   = (w >> 1) * 64;
    const int m0   = by * BM;
    const int n0   = bx * 128;

    floatx4 zero = {0.0f, 0.0f, 0.0f, 0.0f};
    floatx4 acc[AI][4];
#pragma unroll
    for (int i = 0; i < AI; ++i)
#pragma unroll
        for (int j = 0; j < 4; ++j) acc[i][j] = zero;

    const int srow = lane >> 3;
    const int sk   = ((lane & 7) ^ srow) * 8;
    const int fr   = lane & 15;
    const int fx   = fr & 7;

    for (int k0 = 0; k0 < K; k0 += 64) {
        const bf16_t* Abase; int lda, koff;
        if (k0 < xlim) { Abase = Ax; lda = ldX;   koff = k0; }
        else           { Abase = Ah; lda = ldHin; koff = k0 - xlim; }
        const bf16_t* Ag = Abase + (size_t)(m0 + srow) * lda + sk + koff;
        const bf16_t* Bg = W + (size_t)(n0 + srow) * 1152 + sk + k0;
        __syncthreads();
#pragma unroll
        for (int j = 0; j < AI; ++j) {
            int r0 = (w * AI + j) * 8;
            gload_lds16(Ag + (size_t)r0 * lda, As + r0 * 64 + lane * 8);
        }
#pragma unroll
        for (int j = 0; j < 4; ++j) {
            int r0 = (w * 4 + j) * 8;
            gload_lds16(Bg + (size_t)r0 * 1152, Bs + r0 * 64 + lane * 8);
        }
        __syncthreads();
#pragma unroll
        for (int kk = 0; kk < 64; kk += 32) {
            const int pc = ((((kk >> 3) + (lane >> 4)) ^ fx) << 3);
            bf16x8 af[AI], bfr[4];
#pragma unroll
            for (int i = 0; i < AI; ++i)
                af[i] = *(const bf16x8*)(As + (wm + i * 16 + fr) * 64 + pc);
#pragma unroll
            for (int j = 0; j < 4; ++j)
                bfr[j] = *(const bf16x8*)(Bs + (wn + j * 16 + fr) * 64 + pc);
#pragma unroll
            for (int i = 0; i < AI; ++i)
#pragma unroll
                for (int j = 0; j < 4; ++j)
                    acc[i][j] = __builtin_amdgcn_mfma_f32_16x16x32_bf16(af[i], bfr[j], acc[i][j], 0, 0, 0);
        }
    }

    const int crow = (lane >> 4) * 4;
    const int ccol = lane & 15;
    const int e    = ((n0 + wn) >> 2) + ccol;
    float bi[4];
#pragma unroll
    for (int j = 0; j < 4; ++j) bi[j] = bias[n0 + wn + j * 16 + ccol];

#pragma unroll
    for (int i = 0; i < AI; ++i) {
        int tb = m0 + wm + i * 16 + crow;
        floatx4* cp = (floatx4*)(c + (size_t)e * 4096 + tb);
        floatx4 cold = *cp, cnew;
        float hv[4];
#pragma unroll
        for (int r = 0; r < 4; ++r) {
            float iv = acc[i][0][r] + bi[0];
            float fv = acc[i][1][r] + bi[1];
            float gv = acc[i][2][r] + bi[2];
            float ov = acc[i][3][r] + bi[3];
            float cv = sigf(fv) * cold[r] + sigf(iv) * tanhfast(gv);
            cnew[r] = cv;
            float h = sigf(ov) * tanhfast(cv);
            if (relu) h = fmaxf(h, 0.0f);
            hv[r] = h;
        }
        *cp = cnew;
        if (hb) {
#pragma unroll
            for (int r = 0; r < 4; ++r) hb[(size_t)(tb + r) * ldHo + e] = (bf16_t)hv[r];
        } else {
#pragma unroll
            for (int r = 0; r < 4; ++r) hf[(size_t)(tb + r) * ldHo + e] = hv[r];
        }
    }
}

// ================= cooperative mega-kernel (grid-stride, any grid size) =================
__global__ __launch_bounds__(256, 4)
void mega(const float* __restrict__ x,
          const float* __restrict__ eWih, const float* __restrict__ eWhh,
          const float* __restrict__ ebih, const float* __restrict__ ebhh,
          const float* __restrict__ dWih, const float* __restrict__ dWhh,
          const float* __restrict__ dbih, const float* __restrict__ dbhh,
          char* __restrict__ ws, float* __restrict__ out)
{
    __shared__ bf16_t As[128 * 64];
    __shared__ bf16_t Bs[128 * 64];

    bf16_t* Xpad = (bf16_t*)(ws);                 // 4096x128 bf16
    bf16_t* He0  = (bf16_t*)(ws + 1048576);       // 4096x1024 bf16
    bf16_t* He1  = (bf16_t*)(ws + 9437184);
    bf16_t* E    = (bf16_t*)(ws + 17825792);
    bf16_t* Hd0  = (bf16_t*)(ws + 26214400);      // 4096x128 bf16
    bf16_t* Hd1  = (bf16_t*)(ws + 27262976);
    bf16_t* Wenc = (bf16_t*)(ws + 28311552);      // 4x4096x1152 bf16
    bf16_t* Wdec = (bf16_t*)(ws + 66060288);      // 4x512x1152 bf16
    float*  bse  = (float*) (ws + 70778880);      // 16384
    float*  bsd  = (float*) (ws + 70844416);      // 2048
    float*  cenc = (float*) (ws + 70852608);      // [1024][4096]
    float*  cdec = (float*) (ws + 87629824);      // [128][4096]
    float*  hdec = (float*) (ws + 89726976);      // 4096x128 f32

    cg::grid_group grid = cg::this_grid();
    const int G    = gridDim.x;
    const int bid  = blockIdx.x;
    const int gtid = bid * 256 + threadIdx.x;
    const int P    = G * 256;

    // ---- phase 0: pack weights/bias/x, zero states ----
    for (int u = gtid; u < 16384 * 144; u += P) {
        int row = u / 144, grp = u - row * 144;
        int l = row >> 12, p = row & 4095;
        int g = (p >> 4) & 3, e = ((p >> 6) << 4) + (p & 15);
        int c0 = grp * 8;
        float v[8];
#pragma unroll
        for (int k = 0; k < 8; ++k) v[k] = 0.0f;
        if (e < 1000) {
            size_t r = (size_t)l * 4000 + g * 1000 + e;
            if (c0 >= 128 && c0 < 1128) {
                const float* src = eWhh + r * 1000 + (c0 - 128);
                float4 a = *(const float4*)src;
                float4 b = *(const float4*)(src + 4);
                v[0]=a.x; v[1]=a.y; v[2]=a.z; v[3]=a.w; v[4]=b.x; v[5]=b.y; v[6]=b.z; v[7]=b.w;
            } else if (c0 < 128) {
                const float* src = eWih + r * 101;
#pragma unroll
                for (int k = 0; k < 8; ++k) { int cc = c0 + k; if (cc < 101) v[k] = src[cc]; }
            }
        }
        bf16x8 o;
#pragma unroll
        for (int k = 0; k < 8; ++k) o[k] = (bf16_t)v[k];
        *(bf16x8*)(Wenc + (size_t)row * 1152 + c0) = o;
    }
    for (int u = gtid; u < 2048 * 144; u += P) {
        int row = u / 144, grp = u - row * 144;
        int l = row >> 9, p = row & 511;
        int g = (p >> 4) & 3, e = ((p >> 6) << 4) + (p & 15);
        int c0 = grp * 8;
        float v[8];
#pragma unroll
        for (int k = 0; k < 8; ++k) v[k] = 0.0f;
        if (e < 101) {
            size_t r = (size_t)l * 404 + g * 101 + e;
            if (c0 < 1000) {
                const float* src = dWih + r * 1000 + c0;
                float4 a = *(const float4*)src;
                float4 b = *(const float4*)(src + 4);
                v[0]=a.x; v[1]=a.y; v[2]=a.z; v[3]=a.w; v[4]=b.x; v[5]=b.y; v[6]=b.z; v[7]=b.w;
            } else if (c0 >= 1024 && c0 < 1128) {
                const float* src = dWhh + r * 101;
#pragma unroll
                for (int k = 0; k < 8; ++k) { int cc = c0 + k; if (cc < 1125) v[k] = src[cc - 1024]; }
            }
        }
        bf16x8 o;
#pragma unroll
        for (int k = 0; k < 8; ++k) o[k] = (bf16_t)v[k];
        *(bf16x8*)(Wdec + (size_t)row * 1152 + c0) = o;
    }
    for (int u = gtid; u < 65536; u += P) {
        int row = u >> 4, c0 = (u & 15) * 8;
        float v[8];
#pragma unroll
        for (int k = 0; k < 8; ++k) v[k] = 0.0f;
        if (c0 < 101) {
            const float* src = x + (size_t)row * 101;
#pragma unroll
            for (int k = 0; k < 8; ++k) { int cc = c0 + k; if (cc < 101) v[k] = src[cc]; }
        }
        bf16x8 o;
#pragma unroll
        for (int k = 0; k < 8; ++k) o[k] = (bf16_t)v[k];
        *(bf16x8*)(Xpad + (size_t)row * 128 + c0) = o;
    }
    for (int u = gtid; u < 524288 + 65536 + 1048576 + 131072; u += P) {
        float4 z = {0.0f, 0.0f, 0.0f, 0.0f};
        if      (u < 524288)                    ((float4*)He0)[u] = z;
        else if (u < 524288 + 65536)            ((float4*)Hd0)[u - 524288] = z;
        else if (u < 524288 + 65536 + 1048576)  ((float4*)cenc)[u - 524288 - 65536] = z;
        else                                    ((float4*)cdec)[u - 524288 - 65536 - 1048576] = z;
    }
    for (int u = gtid; u < 18432; u += P) {
        if (u < 16384) {
            int l = u >> 12, p = u & 4095;
            int g = (p >> 4) & 3, e = ((p >> 6) << 4) + (p & 15);
            bse[u] = (e < 1000) ? (ebih[l * 4000 + g * 1000 + e] + ebhh[l * 4000 + g * 1000 + e]) : 0.0f;
        } else {
            int k = u - 16384;
            int l = k >> 9, p = k & 511;
            int g = (p >> 4) & 3, e = ((p >> 6) << 4) + (p & 15);
            bsd[k] = (e < 101) ? (dbih[l * 404 + g * 101 + e] + dbhh[l * 404 + g * 101 + e]) : 0.0f;
        }
    }
    __threadfence();
    grid.sync();

    // ---- encoder: 4 layers, 1024 tiles (32x32), grid-stride ----
    for (int l = 0; l < 4; ++l) {
        const bf16_t* Hin = (l & 1) ? He1 : He0;
        bf16_t* hbout; int relu = 0;
        if (l < 3) hbout = (l & 1) ? He0 : He1;
        else { hbout = E; relu = 1; }
        for (int t = bid; t < 1024; t += G)
            gemm_lstm_phase<128>(Xpad, 128, 128, Hin, 1024,
                                 Wenc + (size_t)l * 4096 * 1152, bse + l * 4096,
                                 cenc, hbout, nullptr, 1024, relu,
                                 t & 31, t >> 5, As, Bs);
        __threadfence();
        grid.sync();
    }
    // ---- decoder: 4 layers, 256 tiles (4x64, BM=64), grid-stride ----
    for (int l = 0; l < 4; ++l) {
        const bf16_t* Hin = (l & 1) ? Hd1 : Hd0;
        bf16_t* hbout = nullptr; float* hfout = nullptr;
        if (l < 3) hbout = (l & 1) ? Hd0 : Hd1;
        else hfout = hdec;
        for (int t = bid; t < 256; t += G)
            gemm_lstm_phase<64>(E, 1024, 1024, Hin, 128,
                                Wdec + (size_t)l * 512 * 1152, bsd + l * 512,
                                cdec, hbout, hfout, 128, 0,
                                t & 3, t >> 2, As, Bs);
        __threadfence();
        grid.sync();
    }
    // ---- log_softmax: 4096 rows, one wave per row, grid-stride ----
    {
        const int w    = threadIdx.x >> 6;
        const int lane = threadIdx.x & 63;
        for (int rg = bid; rg < 1024; rg += G) {
            const int row = rg * 4 + w;
            const float* hr = hdec + (size_t)row * 128;
            float v1 = (lane < 101)      ? hr[lane]      : -INFINITY;
            float v2 = (lane + 64 < 101) ? hr[lane + 64] : -INFINITY;
            float m = fmaxf(v1, v2);
#pragma unroll
            for (int off = 32; off > 0; off >>= 1) m = fmaxf(m, __shfl_down(m, off));
            m = __shfl(m, 0);
            float ev = ((lane < 101) ? __expf(v1 - m) : 0.0f) + ((lane + 64 < 101) ? __expf(v2 - m) : 0.0f);
#pragma unroll
            for (int off = 32; off > 0; off >>= 1) ev += __shfl_down(ev, off);
            float lse = m + __logf(__shfl(ev, 0));
            float* orow = out + (size_t)row * 101;
            if (lane < 101)      orow[lane]      = v1 - lse;
            if (lane + 64 < 101) orow[lane + 64] = v2 - lse;
        }
    }
}

// ================= fallback path: R4 multi-kernel (known-good, 407 µs) =================
template<int BM>
__global__ __launch_bounds__(256, 4)
void gemm_lstm(const bf16_t* __restrict__ A, const bf16_t* __restrict__ B,
               const float* __restrict__ bias, float* __restrict__ c, int EP,
               bf16_t* __restrict__ hb, int ldH, int hoff, float* __restrict__ hf,
               int K, int ldA, int ldB, int relu)
{
    constexpr int AI = BM / 32;
    __shared__ bf16_t As[BM * 64];
    __shared__ bf16_t Bs[128 * 64];
    const int tid  = threadIdx.x;
    const int lane = tid & 63;
    const int w    = tid >> 6;
    const int wm   = (w & 1) * (BM / 2);
    const int wn   = (w >> 1) * 64;
    const int m0   = blockIdx.y * BM;
    const int n0   = blockIdx.x * 128;

    floatx4 zero = {0.0f, 0.0f, 0.0f, 0.0f};
    floatx4 acc[AI][4];
#pragma unroll
    for (int i = 0; i < AI; ++i)
#pragma unroll
        for (int j = 0; j < 4; ++j) acc[i][j] = zero;

    const int srow = lane >> 3;
    const int sk   = ((lane & 7) ^ srow) * 8;
    const int fr   = lane & 15;
    const int fx   = fr & 7;

    const bf16_t* Ag = A + (size_t)(m0 + srow) * ldA + sk;
    const bf16_t* Bg = B + (size_t)(n0 + srow) * ldB + sk;

    for (int k0 = 0; k0 < K; k0 += 64) {
        __syncthreads();
#pragma unroll
        for (int j = 0; j < AI; ++j) {
            int r0 = (w * AI + j) * 8;
            gload_lds16(Ag + (size_t)r0 * ldA + k0, As + r0 * 64 + lane * 8);
        }
#pragma unroll
        for (int j = 0; j < 4; ++j) {
            int r0 = (w * 4 + j) * 8;
            gload_lds16(Bg + (size_t)r0 * ldB + k0, Bs + r0 * 64 + lane * 8);
        }
        __syncthreads();
#pragma unroll
        for (int kk = 0; kk < 64; kk += 32) {
            const int pc = ((((kk >> 3) + (lane >> 4)) ^ fx) << 3);
            bf16x8 af[AI], bfr[4];
#pragma unroll
            for (int i = 0; i < AI; ++i)
                af[i] = *(const bf16x8*)(As + (wm + i * 16 + fr) * 64 + pc);
#pragma unroll
            for (int j = 0; j < 4; ++j)
                bfr[j] = *(const bf16x8*)(Bs + (wn + j * 16 + fr) * 64 + pc);
#pragma unroll
            for (int i = 0; i < AI; ++i)
#pragma unroll
                for (int j = 0; j < 4; ++j)
                    acc[i][j] = __builtin_amdgcn_mfma_f32_16x16x32_bf16(af[i], bfr[j], acc[i][j], 0, 0, 0);
        }
    }

    const int crow = (lane >> 4) * 4;
    const int ccol = lane & 15;
    const int e    = ((n0 + wn) >> 2) + ccol;
    float bi[4];
#pragma unroll
    for (int j = 0; j < 4; ++j) bi[j] = bias[n0 + wn + j * 16 + ccol];

#pragma unroll
    for (int i = 0; i < AI; ++i) {
#pragma unroll
        for (int r = 0; r < 4; ++r) {
            int t = m0 + wm + i * 16 + crow + r;
            float iv = acc[i][0][r] + bi[0];
            float fv = acc[i][1][r] + bi[1];
            float gv = acc[i][2][r] + bi[2];
            float ov = acc[i][3][r] + bi[3];
            size_t cix = (size_t)t * EP + e;
            float cv = sigf(fv) * c[cix] + sigf(iv) * tanhfast(gv);
            c[cix] = cv;
            float hv = sigf(ov) * tanhfast(cv);
            if (relu) hv = fmaxf(hv, 0.0f);
            if (hb) hb[(size_t)t * ldH + hoff + e] = (bf16_t)hv;
            else    hf[(size_t)t * EP + e] = hv;
        }
    }
}

__global__ void pack_xz(const float* __restrict__ x, bf16_t* __restrict__ Aenc)
{
    int gid = blockIdx.x * 256 + threadIdx.x;
    int row = gid / 144, grp = gid - row * 144;
    int c0  = grp * 8;
    float v[8];
#pragma unroll
    for (int u = 0; u < 8; ++u) v[u] = 0.0f;
    if (c0 < 101) {
        const float* src = x + (size_t)row * 101;
#pragma unroll
        for (int u = 0; u < 8; ++u) { int cc = c0 + u; if (cc < 101) v[u] = src[cc]; }
    }
    bf16x8 o;
#pragma unroll
    for (int u = 0; u < 8; ++u) o[u] = (bf16_t)v[u];
    *(bf16x8*)(Aenc + (size_t)row * 1152 + c0) = o;
}

__global__ void pack_wenc(const float* __restrict__ Wih, const float* __restrict__ Whh,
                          bf16_t* __restrict__ W)
{
    int gid = blockIdx.x * 256 + threadIdx.x;
    int row = gid / 144, grp = gid - row * 144;
    int l = row >> 12, p = row & 4095;
    int g = (p >> 4) & 3, e = ((p >> 6) << 4) + (p & 15);
    int c0 = grp * 8;
    float v[8];
#pragma unroll
    for (int u = 0; u < 8; ++u) v[u] = 0.0f;
    if (e < 1000) {
        size_t r = (size_t)l * 4000 + g * 1000 + e;
        if (c0 >= 128 && c0 < 1128) {
            const float* src = Whh + r * 1000 + (c0 - 128);
            float4 a = *(const float4*)src;
            float4 b = *(const float4*)(src + 4);
            v[0]=a.x; v[1]=a.y; v[2]=a.z; v[3]=a.w; v[4]=b.x; v[5]=b.y; v[6]=b.z; v[7]=b.w;
        } else if (c0 < 128) {
            const float* src = Wih + r * 101;
#pragma unroll
            for (int u = 0; u < 8; ++u) { int cc = c0 + u; if (cc < 101) v[u] = src[cc]; }
        }
    }
    bf16x8 o;
#pragma unroll
    for (int u = 0; u < 8; ++u) o[u] = (bf16_t)v[u];
    *(bf16x8*)(W + (size_t)row * 1152 + c0) = o;
}

__global__ void pack_wdec(const float* __restrict__ Wih, const float* __restrict__ Whh,
                          bf16_t* __restrict__ W)
{
    int gid = blockIdx.x * 256 + threadIdx.x;
    int row = gid / 144, grp = gid - row * 144;
    int l = row >> 9, p = row & 511;
    int g = (p >> 4) & 3, e = ((p >> 6) << 4) + (p & 15);
    int c0 = grp * 8;
    float v[8];
#pragma unroll
    for (int u = 0; u < 8; ++u) v[u] = 0.0f;
    if (e < 101) {
        size_t r = (size_t)l * 404 + g * 101 + e;
        if (c0 < 1000) {
            const float* src = Wih + r * 1000 + c0;
            float4 a = *(const float4*)src;
            float4 b = *(const float4*)(src + 4);
            v[0]=a.x; v[1]=a.y; v[2]=a.z; v[3]=a.w; v[4]=b.x; v[5]=b.y; v[6]=b.z; v[7]=b.w;
        } else if (c0 >= 1024 && c0 < 1128) {
            const float* src = Whh + r * 101;
#pragma unroll
            for (int u = 0; u < 8; ++u) { int cc = c0 + u; if (cc < 1125) v[u] = src[cc - 1024]; }
        }
    }
    bf16x8 o;
#pragma unroll
    for (int u = 0; u < 8; ++u) o[u] = (bf16_t)v[u];
    *(bf16x8*)(W + (size_t)row * 1152 + c0) = o;
}

__global__ void pack_b(const float* __restrict__ ebih, const float* __restrict__ ebhh,
                       const float* __restrict__ dbih, const float* __restrict__ dbhh,
                       float* __restrict__ bse, float* __restrict__ bsd)
{
    int idx = blockIdx.x * 256 + threadIdx.x;
    if (idx < 16384) {
        int l = idx >> 12, p = idx & 4095;
        int g = (p >> 4) & 3, e = ((p >> 6) << 4) + (p & 15);
        bse[idx] = (e < 1000) ? (ebih[l * 4000 + g * 1000 + e] + ebhh[l * 4000 + g * 1000 + e]) : 0.0f;
    } else {
        int k = idx - 16384;
        int l = k >> 9, p = k & 511;
        int g = (p >> 4) & 3, e = ((p >> 6) << 4) + (p & 15);
        bsd[k] = (e < 101) ? (dbih[l * 404 + g * 101 + e] + dbhh[l * 404 + g * 101 + e]) : 0.0f;
    }
}

__global__ void zero_misc(float* __restrict__ cenc, float* __restrict__ cdec,
                          bf16_t* __restrict__ Adec)
{
    int gid = blockIdx.x * 256 + threadIdx.x;
    float4 z = {0.0f, 0.0f, 0.0f, 0.0f};
    if (gid < 1048576) {
        ((float4*)cenc)[gid] = z;
    } else if (gid < 1179648) {
        ((float4*)cdec)[gid - 1048576] = z;
    } else {
        int k = gid - 1179648;
        int row = k >> 4, off = (k & 15) * 8;
        *(float4*)(Adec + (size_t)row * 1152 + 1024 + off) = z;
    }
}

__global__ void log_softmax_k(const float* __restrict__ h, float* __restrict__ out)
{
    int row = blockIdx.x;
    int l   = threadIdx.x;
    const float* hr = h + (size_t)row * 128;
    float v1 = (l < 101)      ? hr[l]      : -INFINITY;
    float v2 = (l + 64 < 101) ? hr[l + 64] : -INFINITY;
    float m = fmaxf(v1, v2);
#pragma unroll
    for (int off = 32; off > 0; off >>= 1) m = fmaxf(m, __shfl_down(m, off));
    m = __shfl(m, 0);
    float ev = ((l < 101) ? __expf(v1 - m) : 0.0f) + ((l + 64 < 101) ? __expf(v2 - m) : 0.0f);
#pragma unroll
    for (int off = 32; off > 0; off >>= 1) ev += __shfl_down(ev, off);
    float lse = m + __logf(__shfl(ev, 0));
    float* orow = out + (size_t)row * 101;
    if (l < 101)      orow[l]      = v1 - lse;
    if (l + 64 < 101) orow[l + 64] = v2 - lse;
}

extern "C" void kernel_launch(void* const* d_in, const int* in_sizes, int n_in,
                              void* d_out, int out_size, void* d_ws, size_t ws_size,
                              hipStream_t stream)
{
    (void)in_sizes; (void)n_in; (void)out_size; (void)ws_size;
    const float* x    = (const float*)d_in[0];
    const float* eWih = (const float*)d_in[1];
    const float* eWhh = (const float*)d_in[2];
    const float* ebih = (const float*)d_in[3];
    const float* ebhh = (const float*)d_in[4];
    const float* dWih = (const float*)d_in[5];
    const float* dWhh = (const float*)d_in[6];
    const float* dbih = (const float*)d_in[7];
    const float* dbhh = (const float*)d_in[8];
    char* ws    = (char*)d_ws;
    float* outp = (float*)d_out;

    // --- try the cooperative mega-kernel, grid sized from an occupancy query ---
    int maxPerCU = 0;
    (void)hipOccupancyMaxActiveBlocksPerMultiprocessor(&maxPerCU, mega, 256, 0);
    int dev = 0;
    (void)hipGetDevice(&dev);
    int numCU = 0;
    (void)hipDeviceGetAttribute(&numCU, hipDeviceAttributeMultiprocessorCount, dev);
    long cap = (long)maxPerCU * (long)numCU;
    int nblk = (cap > 1024) ? 1024 : (int)cap;

    hipError_t err = hipErrorUnknown;
    if (nblk >= 64) {
        void* args[] = {
            (void*)&x, (void*)&eWih, (void*)&eWhh, (void*)&ebih, (void*)&ebhh,
            (void*)&dWih, (void*)&dWhh, (void*)&dbih, (void*)&dbhh,
            (void*)&ws, (void*)&outp
        };
        err = hipLaunchCooperativeKernel((const void*)mega, dim3(nblk), dim3(256),
                                         args, 0, stream);
    }
    if (err == hipSuccess) return;

    // --- fallback: proven R4 multi-kernel path (distinct ws layout) ---
    bf16_t* Aenc = (bf16_t*)(ws);
    bf16_t* Wenc = (bf16_t*)(ws + 9437184);
    bf16_t* Adec = (bf16_t*)(ws + 47185920);
    bf16_t* Wdec = (bf16_t*)(ws + 56623104);
    float*  bse  = (float*) (ws + 61341696);
    float*  bsd  = (float*) (ws + 61407232);
    float*  cenc = (float*) (ws + 61415424);
    float*  cdec = (float*) (ws + 78192640);
    float*  hdec = (float*) (ws + 80289792);

    zero_misc<<<4864, 256, 0, stream>>>(cenc, cdec, Adec);
    pack_xz  <<<2304, 256, 0, stream>>>(x, Aenc);
    pack_wenc<<<9216, 256, 0, stream>>>(eWih, eWhh, Wenc);
    pack_wdec<<<1152, 256, 0, stream>>>(dWih, dWhh, Wdec);
    pack_b   <<<72,   256, 0, stream>>>(ebih, ebhh, dbih, dbhh, bse, bsd);

    for (int l = 0; l < 4; ++l) {
        gemm_lstm<128><<<dim3(32, 32), 256, 0, stream>>>(
            Aenc, Wenc + (size_t)l * 4096 * 1152, bse + l * 4096,
            cenc, 1024,
            (l < 3) ? Aenc : Adec, 1152, (l < 3) ? 128 : 0, nullptr,
            1152, 1152, 1152, (l == 3) ? 1 : 0);
    }
    for (int l = 0; l < 4; ++l) {
        gemm_lstm<64><<<dim3(4, 64), 256, 0, stream>>>(
            Adec, Wdec + (size_t)l * 512 * 1152, bsd + l * 512,
            cdec, 128,
            (l < 3) ? Adec : nullptr, 1152, 1024, (l == 3) ? hdec : nullptr,
            1152, 1152, 1152, 0);
    }
    log_softmax_k<<<4096, 64, 0, stream>>>(hdec, (float*)d_out);
}

// Round 8
// 505.226 us; speedup vs baseline: 3.0172x; 3.0172x over previous
//
#include <hip/hip_runtime.h>
#include <cstdint>
#include <cstddef>
#include <cmath>

typedef __bf16 bf16_t;
typedef __bf16 bf16x8 __attribute__((ext_vector_type(8)));
typedef float floatx4 __attribute__((ext_vector_type(4)));

#define AS1 __attribute__((address_space(1)))
#define AS3 __attribute__((address_space(3)))

__device__ __forceinline__ void gload_lds16(const bf16_t* g, bf16_t* l) {
    __builtin_amdgcn_global_load_lds((AS1 void*)(uintptr_t)(g), (AS3 void*)(l), 16, 0, 0);
}

__device__ __forceinline__ float sigf(float x) { return 1.0f / (1.0f + __expf(-x)); }
__device__ __forceinline__ float tanhfast(float x) { return 1.0f - 2.0f / (__expf(2.0f * x) + 1.0f); }

// ================= encoder GEMM+LSTM (one dispatch per layer) =================
// gates(M x N) = A(M,K) @ W(N,K)^T + bias(N); LSTM cell fused in epilogue.
// Gate-interleaved W packing: lane's acc[i][0..3] = (i,f,g,o) of element
// e = ((n0+wn)>>2)+(lane&15). LDS XOR swizzle: phys 16B chunk = logical^(row&7);
// staging keeps the mandatory linear base+lane*16 global_load_lds pattern by
// permuting per-lane *global* addresses (still intra-128B-segment coalesced).
// RACE-FREE: h is written to a DIFFERENT buffer (A ping-pong) than A being read.
template<int BM>
__global__ __launch_bounds__(256, 4)
void gemm_lstm(const bf16_t* __restrict__ A, const bf16_t* __restrict__ B,
               const float* __restrict__ bias, float* __restrict__ c, int EP,
               bf16_t* __restrict__ hb, int ldH, int hoff, float* __restrict__ hf,
               int K, int ldA, int ldB, int relu)
{
    constexpr int AI = BM / 32;
    __shared__ bf16_t As[BM * 64];
    __shared__ bf16_t Bs[128 * 64];
    const int tid  = threadIdx.x;
    const int lane = tid & 63;
    const int w    = tid >> 6;
    const int wm   = (w & 1) * (BM / 2);
    const int wn   = (w >> 1) * 64;
    const int m0   = blockIdx.y * BM;
    const int n0   = blockIdx.x * 128;

    floatx4 zero = {0.0f, 0.0f, 0.0f, 0.0f};
    floatx4 acc[AI][4];
#pragma unroll
    for (int i = 0; i < AI; ++i)
#pragma unroll
        for (int j = 0; j < 4; ++j) acc[i][j] = zero;

    const int srow = lane >> 3;
    const int sk   = ((lane & 7) ^ srow) * 8;
    const int fr   = lane & 15;
    const int fx   = fr & 7;

    const bf16_t* Ag = A + (size_t)(m0 + srow) * ldA + sk;
    const bf16_t* Bg = B + (size_t)(n0 + srow) * ldB + sk;

    for (int k0 = 0; k0 < K; k0 += 64) {
        __syncthreads();
#pragma unroll
        for (int j = 0; j < AI; ++j) {
            int r0 = (w * AI + j) * 8;
            gload_lds16(Ag + (size_t)r0 * ldA + k0, As + r0 * 64 + lane * 8);
        }
#pragma unroll
        for (int j = 0; j < 4; ++j) {
            int r0 = (w * 4 + j) * 8;
            gload_lds16(Bg + (size_t)r0 * ldB + k0, Bs + r0 * 64 + lane * 8);
        }
        __syncthreads();
#pragma unroll
        for (int kk = 0; kk < 64; kk += 32) {
            const int pc = ((((kk >> 3) + (lane >> 4)) ^ fx) << 3);
            bf16x8 af[AI], bfr[4];
#pragma unroll
            for (int i = 0; i < AI; ++i)
                af[i] = *(const bf16x8*)(As + (wm + i * 16 + fr) * 64 + pc);
#pragma unroll
            for (int j = 0; j < 4; ++j)
                bfr[j] = *(const bf16x8*)(Bs + (wn + j * 16 + fr) * 64 + pc);
#pragma unroll
            for (int i = 0; i < AI; ++i)
#pragma unroll
                for (int j = 0; j < 4; ++j)
                    acc[i][j] = __builtin_amdgcn_mfma_f32_16x16x32_bf16(af[i], bfr[j], acc[i][j], 0, 0, 0);
        }
    }

    // Epilogue. C/D layout: col = lane&15, row = (lane>>4)*4 + reg.
    const int crow = (lane >> 4) * 4;
    const int ccol = lane & 15;
    const int e    = ((n0 + wn) >> 2) + ccol;
    float bi[4];
#pragma unroll
    for (int j = 0; j < 4; ++j) bi[j] = bias[n0 + wn + j * 16 + ccol];

#pragma unroll
    for (int i = 0; i < AI; ++i) {
#pragma unroll
        for (int r = 0; r < 4; ++r) {
            int t = m0 + wm + i * 16 + crow + r;
            float iv = acc[i][0][r] + bi[0];
            float fv = acc[i][1][r] + bi[1];
            float gv = acc[i][2][r] + bi[2];
            float ov = acc[i][3][r] + bi[3];
            size_t cix = (size_t)t * EP + e;
            float cv = sigf(fv) * c[cix] + sigf(iv) * tanhfast(gv);
            c[cix] = cv;
            float hv = sigf(ov) * tanhfast(cv);
            if (relu) hv = fmaxf(hv, 0.0f);
            if (hb) hb[(size_t)t * ldH + hoff + e] = (bf16_t)hv;
            else    hf[(size_t)t * EP + e] = hv;
        }
    }
}

// ================= decoder: all 4 layers + softmax in ONE dispatch =================
// 256 blocks (4 N-tiles x 64 M-tiles, BM=64). Layers joined by a custom
// inter-block barrier (atomicAdd + s_sleep spin; 256 blocks <= 1/4 residency
// capacity so all are co-resident; counter zeroed by prep). c stays in
// REGISTERS across layers; h ping-pongs Hd0/Hd1 (layer 0 reads zeroed Hd0).
__device__ __forceinline__ void gbar(int* bar, int target)
{
    __syncthreads();
    if (threadIdx.x == 0) {
        __threadfence();                  // release: flush this XCD's L2
        atomicAdd(bar, 1);
        while (atomicAdd(bar, 0) < target) __builtin_amdgcn_s_sleep(8);
    }
    __syncthreads();
    __threadfence();                      // acquire: invalidate stale lines
}

__global__ __launch_bounds__(256, 4)
void dec_all(const bf16_t* __restrict__ E, const bf16_t* __restrict__ Wd,
             const float* __restrict__ bsd,
             bf16_t* __restrict__ Hd0, bf16_t* __restrict__ Hd1,
             float* __restrict__ hdec, float* __restrict__ out,
             int* __restrict__ bar)
{
    __shared__ bf16_t As[64 * 64];
    __shared__ bf16_t Bs[128 * 64];
    const int tid  = threadIdx.x;
    const int lane = tid & 63;
    const int w    = tid >> 6;
    const int bid  = blockIdx.x;
    const int G    = gridDim.x;           // 256
    const int bx   = bid & 3, by = bid >> 2;
    const int wm   = (w & 1) * 32;
    const int wn   = (w >> 1) * 64;
    const int m0   = by * 64;
    const int n0   = bx * 128;
    const int srow = lane >> 3;
    const int sk   = ((lane & 7) ^ srow) * 8;
    const int fr   = lane & 15;
    const int fx   = fr & 7;
    const int crow = (lane >> 4) * 4;
    const int ccol = lane & 15;
    const int e    = ((n0 + wn) >> 2) + ccol;

    floatx4 zero = {0.0f, 0.0f, 0.0f, 0.0f};
    floatx4 creg[2] = {zero, zero};       // cell state lives in registers

    for (int l = 0; l < 4; ++l) {
        const bf16_t* W   = Wd + (size_t)l * 512 * 1152;
        const bf16_t* Hin = (l & 1) ? Hd1 : Hd0;
        floatx4 acc[2][4];
#pragma unroll
        for (int i = 0; i < 2; ++i)
#pragma unroll
            for (int j = 0; j < 4; ++j) acc[i][j] = zero;

        for (int k0 = 0; k0 < 1152; k0 += 64) {
            const bf16_t* Abase; int lda, koff;
            if (k0 < 1024) { Abase = E;   lda = 1024; koff = k0; }
            else           { Abase = Hin; lda = 128;  koff = k0 - 1024; }
            const bf16_t* Ag = Abase + (size_t)(m0 + srow) * lda + sk + koff;
            const bf16_t* Bg = W + (size_t)(n0 + srow) * 1152 + sk + k0;
            __syncthreads();
#pragma unroll
            for (int j = 0; j < 2; ++j) {
                int r0 = (w * 2 + j) * 8;
                gload_lds16(Ag + (size_t)r0 * lda, As + r0 * 64 + lane * 8);
            }
#pragma unroll
            for (int j = 0; j < 4; ++j) {
                int r0 = (w * 4 + j) * 8;
                gload_lds16(Bg + (size_t)r0 * 1152, Bs + r0 * 64 + lane * 8);
            }
            __syncthreads();
#pragma unroll
            for (int kk = 0; kk < 64; kk += 32) {
                const int pc = ((((kk >> 3) + (lane >> 4)) ^ fx) << 3);
                bf16x8 af[2], bfr[4];
#pragma unroll
                for (int i = 0; i < 2; ++i)
                    af[i] = *(const bf16x8*)(As + (wm + i * 16 + fr) * 64 + pc);
#pragma unroll
                for (int j = 0; j < 4; ++j)
                    bfr[j] = *(const bf16x8*)(Bs + (wn + j * 16 + fr) * 64 + pc);
#pragma unroll
                for (int i = 0; i < 2; ++i)
#pragma unroll
                    for (int j = 0; j < 4; ++j)
                        acc[i][j] = __builtin_amdgcn_mfma_f32_16x16x32_bf16(af[i], bfr[j], acc[i][j], 0, 0, 0);
            }
        }

        const float* bias = bsd + l * 512;
        float bi[4];
#pragma unroll
        for (int j = 0; j < 4; ++j) bi[j] = bias[n0 + wn + j * 16 + ccol];
        bf16_t* Hout = (l & 1) ? Hd0 : Hd1;
#pragma unroll
        for (int i = 0; i < 2; ++i) {
            int tb = m0 + wm + i * 16 + crow;
            floatx4 cnew;
#pragma unroll
            for (int r = 0; r < 4; ++r) {
                float iv = acc[i][0][r] + bi[0];
                float fv = acc[i][1][r] + bi[1];
                float gv = acc[i][2][r] + bi[2];
                float ov = acc[i][3][r] + bi[3];
                float cv = sigf(fv) * creg[i][r] + sigf(iv) * tanhfast(gv);
                cnew[r] = cv;
                float hv = sigf(ov) * tanhfast(cv);
                if (l < 3) Hout[(size_t)(tb + r) * 128 + e] = (bf16_t)hv;
                else       hdec[(size_t)(tb + r) * 128 + e] = hv;
            }
            creg[i] = cnew;
        }
        gbar(bar, (l + 1) * G);
    }

    // ---- log_softmax over 101 valid cols (stride 128), one wave per row ----
    for (int rb = bid; rb < 1024; rb += G) {
        const int row = rb * 4 + w;
        const float* hr = hdec + (size_t)row * 128;
        float v1 = (lane < 101)      ? hr[lane]      : -INFINITY;
        float v2 = (lane + 64 < 101) ? hr[lane + 64] : -INFINITY;
        float m = fmaxf(v1, v2);
#pragma unroll
        for (int off = 32; off > 0; off >>= 1) m = fmaxf(m, __shfl_down(m, off));
        m = __shfl(m, 0);
        float ev = ((lane < 101) ? __expf(v1 - m) : 0.0f) + ((lane + 64 < 101) ? __expf(v2 - m) : 0.0f);
#pragma unroll
        for (int off = 32; off > 0; off >>= 1) ev += __shfl_down(ev, off);
        float lse = m + __logf(__shfl(ev, 0));
        float* orow = out + (size_t)row * 101;
        if (lane < 101)      orow[lane]      = v1 - lse;
        if (lane + 64 < 101) orow[lane + 64] = v2 - lse;
    }
}

// ================= ONE prep kernel: packs + zeros + barrier init =================
// A0/A1 (4096 x 1152): [x(0:101) pad(101:128) h(128:1152)]. x+pad written to
// BOTH; h-region of A0 zeroed (layer 0 input h=0); A1 h-region is fully
// overwritten by layer 0's epilogue before layer 1 reads it.
__global__ void prep(const float* __restrict__ x,
                     const float* __restrict__ eWih, const float* __restrict__ eWhh,
                     const float* __restrict__ ebih, const float* __restrict__ ebhh,
                     const float* __restrict__ dWih, const float* __restrict__ dWhh,
                     const float* __restrict__ dbih, const float* __restrict__ dbhh,
                     bf16_t* __restrict__ A0, bf16_t* __restrict__ A1,
                     bf16_t* __restrict__ Hd0,
                     bf16_t* __restrict__ Wenc, bf16_t* __restrict__ Wdec,
                     float* __restrict__ bse, float* __restrict__ bsd,
                     float* __restrict__ cenc, int* __restrict__ bar)
{
    const int gtid = blockIdx.x * 256 + threadIdx.x;
    const int P    = gridDim.x * 256;
    if (gtid == 0) *bar = 0;

    // W_enc: 16384 N-pos x 144 chunks of 8. N-pos p: g=(p>>4)&3,
    // e=((p>>6)<<4)+(p&15); orig row g*1000+e (e<1000). [Wih(0:101) 0 Whh(128:1128) 0]
    for (int u = gtid; u < 16384 * 144; u += P) {
        int row = u / 144, grp = u - row * 144;
        int l = row >> 12, p = row & 4095;
        int g = (p >> 4) & 3, e = ((p >> 6) << 4) + (p & 15);
        int c0 = grp * 8;
        float v[8];
#pragma unroll
        for (int k = 0; k < 8; ++k) v[k] = 0.0f;
        if (e < 1000) {
            size_t r = (size_t)l * 4000 + g * 1000 + e;
            if (c0 >= 128 && c0 < 1128) {
                const float* src = eWhh + r * 1000 + (c0 - 128);
                float4 a = *(const float4*)src;
                float4 b = *(const float4*)(src + 4);
                v[0]=a.x; v[1]=a.y; v[2]=a.z; v[3]=a.w; v[4]=b.x; v[5]=b.y; v[6]=b.z; v[7]=b.w;
            } else if (c0 < 128) {
                const float* src = eWih + r * 101;
#pragma unroll
                for (int k = 0; k < 8; ++k) { int cc = c0 + k; if (cc < 101) v[k] = src[cc]; }
            }
        }
        bf16x8 o;
#pragma unroll
        for (int k = 0; k < 8; ++k) o[k] = (bf16_t)v[k];
        *(bf16x8*)(Wenc + (size_t)row * 1152 + c0) = o;
    }
    // W_dec: 2048 N-pos x 144 chunks; e in [0,128), orig row g*101+e (e<101).
    for (int u = gtid; u < 2048 * 144; u += P) {
        int row = u / 144, grp = u - row * 144;
        int l = row >> 9, p = row & 511;
        int g = (p >> 4) & 3, e = ((p >> 6) << 4) + (p & 15);
        int c0 = grp * 8;
        float v[8];
#pragma unroll
        for (int k = 0; k < 8; ++k) v[k] = 0.0f;
        if (e < 101) {
            size_t r = (size_t)l * 404 + g * 101 + e;
            if (c0 < 1000) {
                const float* src = dWih + r * 1000 + c0;
                float4 a = *(const float4*)src;
                float4 b = *(const float4*)(src + 4);
                v[0]=a.x; v[1]=a.y; v[2]=a.z; v[3]=a.w; v[4]=b.x; v[5]=b.y; v[6]=b.z; v[7]=b.w;
            } else if (c0 >= 1024 && c0 < 1128) {
                const float* src = dWhh + r * 101;
#pragma unroll
                for (int k = 0; k < 8; ++k) { int cc = c0 + k; if (cc < 1125) v[k] = src[cc - 1024]; }
            }
        }
        bf16x8 o;
#pragma unroll
        for (int k = 0; k < 8; ++k) o[k] = (bf16_t)v[k];
        *(bf16x8*)(Wdec + (size_t)row * 1152 + c0) = o;
    }
    // x + pad into A0 AND A1 cols 0..127 (16 chunks/row)
    for (int u = gtid; u < 65536; u += P) {
        int row = u >> 4, c0 = (u & 15) * 8;
        float v[8];
#pragma unroll
        for (int k = 0; k < 8; ++k) v[k] = 0.0f;
        if (c0 < 101) {
            const float* src = x + (size_t)row * 101;
#pragma unroll
            for (int k = 0; k < 8; ++k) { int cc = c0 + k; if (cc < 101) v[k] = src[cc]; }
        }
        bf16x8 o;
#pragma unroll
        for (int k = 0; k < 8; ++k) o[k] = (bf16_t)v[k];
        *(bf16x8*)(A0 + (size_t)row * 1152 + c0) = o;
        *(bf16x8*)(A1 + (size_t)row * 1152 + c0) = o;
    }
    // zero A0 h-region (cols 128..1151): 4096 rows x 128 chunks
    float4 z = {0.0f, 0.0f, 0.0f, 0.0f};
    for (int u = gtid; u < 524288; u += P) {
        int row = u >> 7, c0 = 128 + (u & 127) * 8;
        *(float4*)(A0 + (size_t)row * 1152 + c0) = z;
    }
    // zero Hd0 (1 MB) and cenc (16.7 MB) in 16B chunks
    for (int u = gtid; u < 65536; u += P)   ((float4*)Hd0)[u]  = z;
    for (int u = gtid; u < 1048576; u += P) ((float4*)cenc)[u] = z;
    // bias (gate-interleaved)
    for (int u = gtid; u < 18432; u += P) {
        if (u < 16384) {
            int l = u >> 12, p = u & 4095;
            int g = (p >> 4) & 3, e = ((p >> 6) << 4) + (p & 15);
            bse[u] = (e < 1000) ? (ebih[l * 4000 + g * 1000 + e] + ebhh[l * 4000 + g * 1000 + e]) : 0.0f;
        } else {
            int k = u - 16384;
            int l = k >> 9, p = k & 511;
            int g = (p >> 4) & 3, e = ((p >> 6) << 4) + (p & 15);
            bsd[k] = (e < 101) ? (dbih[l * 404 + g * 101 + e] + dbhh[l * 404 + g * 101 + e]) : 0.0f;
        }
    }
}

extern "C" void kernel_launch(void* const* d_in, const int* in_sizes, int n_in,
                              void* d_out, int out_size, void* d_ws, size_t ws_size,
                              hipStream_t stream)
{
    (void)in_sizes; (void)n_in; (void)out_size; (void)ws_size;
    const float* x    = (const float*)d_in[0];
    const float* eWih = (const float*)d_in[1];
    const float* eWhh = (const float*)d_in[2];
    const float* ebih = (const float*)d_in[3];
    const float* ebhh = (const float*)d_in[4];
    const float* dWih = (const float*)d_in[5];
    const float* dWhh = (const float*)d_in[6];
    const float* dbih = (const float*)d_in[7];
    const float* dbhh = (const float*)d_in[8];
    char* ws = (char*)d_ws;

    bf16_t* A0   = (bf16_t*)(ws);                 // 4096x1152 bf16 =  9,437,184
    bf16_t* A1   = (bf16_t*)(ws + 9437184);       //                   9,437,184
    bf16_t* E    = (bf16_t*)(ws + 18874368);      // 4096x1024 bf16 =  8,388,608
    bf16_t* Hd0  = (bf16_t*)(ws + 27262976);      // 4096x128 bf16  =  1,048,576
    bf16_t* Hd1  = (bf16_t*)(ws + 28311552);      //                   1,048,576
    bf16_t* Wenc = (bf16_t*)(ws + 29360128);      // 4x4096x1152    = 37,748,736
    bf16_t* Wdec = (bf16_t*)(ws + 67108864);      // 4x512x1152     =  4,718,592
    float*  bse  = (float*) (ws + 71827456);      // 16384 f32      =     65,536
    float*  bsd  = (float*) (ws + 71892992);      // 2048 f32       =      8,192
    float*  cenc = (float*) (ws + 71901184);      // 4096x1024 f32  = 16,777,216
    float*  hdec = (float*) (ws + 88678400);      // 4096x128 f32   =  2,097,152
    int*    bar  = (int*)   (ws + 90775552);      // barrier counter (end 90,775,616)

    // 1 prep + 4 encoder + 1 decoder(all layers + softmax) = 6 dispatches
    prep<<<2048, 256, 0, stream>>>(x, eWih, eWhh, ebih, ebhh, dWih, dWhh,
                                   dbih, dbhh, A0, A1, Hd0, Wenc, Wdec,
                                   bse, bsd, cenc, bar);

    // Encoder: A ping-pong (race-free). l=3 writes relu(h) into E.
    for (int l = 0; l < 4; ++l) {
        const bf16_t* Ain = (l & 1) ? A1 : A0;
        bf16_t* hb = (l < 3) ? ((l & 1) ? A0 : A1) : E;
        gemm_lstm<128><<<dim3(32, 32), 256, 0, stream>>>(
            Ain, Wenc + (size_t)l * 4096 * 1152, bse + l * 4096,
            cenc, 1024,
            hb, (l < 3) ? 1152 : 1024, (l < 3) ? 128 : 0, nullptr,
            1152, 1152, 1152, (l == 3) ? 1 : 0);
    }

    // Decoder: all 4 layers + softmax, one dispatch with custom barrier.
    dec_all<<<256, 256, 0, stream>>>(E, Wdec, bsd, Hd0, Hd1, hdec,
                                     (float*)d_out, bar);
}